// Round 4
// baseline (896.523 us; speedup 1.0000x reference)
//
#include <hip/hip_runtime.h>
#include <hip/hip_bf16.h>

typedef __attribute__((ext_vector_type(8))) __bf16 bx8;
typedef __attribute__((ext_vector_type(4))) float  fx4;

#define ROWS 8192   // B*S
#define HID  1024
#define MEMN 8192

// global_load_lds, 16B per lane; LDS dest = wave-uniform base + lane*16
#define GLDS(gp, lp) __builtin_amdgcn_global_load_lds( \
    (const __attribute__((address_space(1))) void*)(gp), \
    (__attribute__((address_space(3))) void*)(lp), 16, 0, 0)

// ---------------------------------------------------------------------------
// fp32 -> bf16 elementwise convert (vectorized, exact grid: n = blocks*256*8)
// ---------------------------------------------------------------------------
__global__ __launch_bounds__(256)
void f32_to_bf16_vec(const float* __restrict__ in, __bf16* __restrict__ out)
{
    const size_t i = ((size_t)blockIdx.x * 256 + threadIdx.x) * 8;
    fx4 a = *(const fx4*)(in + i);
    fx4 b = *(const fx4*)(in + i + 4);
    bx8 u;
    u[0] = (__bf16)a[0]; u[1] = (__bf16)a[1]; u[2] = (__bf16)a[2]; u[3] = (__bf16)a[3];
    u[4] = (__bf16)b[0]; u[5] = (__bf16)b[1]; u[6] = (__bf16)b[2]; u[7] = (__bf16)b[3];
    *(bx8*)(out + i) = u;
}

// ---------------------------------------------------------------------------
// fp32 [R][C] -> bf16 [C][R] transpose (64x64 tiles via LDS)
// ---------------------------------------------------------------------------
__global__ __launch_bounds__(256)
void transpose_f32_to_bf16(const float* __restrict__ in, __bf16* __restrict__ out,
                           int R, int C)
{
    __shared__ float t[64][65];
    const int tid = threadIdx.x;
    const int r0 = blockIdx.y * 64;
    const int c0 = blockIdx.x * 64;
    const int lr = tid >> 4;
    const int lc = (tid & 15) * 4;
#pragma unroll
    for (int p = 0; p < 4; ++p) {
        const int rr = p * 16 + lr;
        const fx4 v = *(const fx4*)(in + (size_t)(r0 + rr) * C + c0 + lc);
        t[rr][lc + 0] = v[0]; t[rr][lc + 1] = v[1];
        t[rr][lc + 2] = v[2]; t[rr][lc + 3] = v[3];
    }
    __syncthreads();
    const int oc = tid >> 2;
    const int ob = (tid & 3) * 16;
    bx8 u0, u1;
#pragma unroll
    for (int j = 0; j < 8; ++j) {
        u0[j] = (__bf16)t[ob + j][oc];
        u1[j] = (__bf16)t[ob + 8 + j][oc];
    }
    *(bx8*)(out + (size_t)(c0 + oc) * R + r0 + ob)     = u0;
    *(bx8*)(out + (size_t)(c0 + oc) * R + r0 + ob + 8) = u1;
}

// ---------------------------------------------------------------------------
// In-place transpose of square bf16 matrix W [MEMN][MEMN], 64x64 tile pairs.
// ---------------------------------------------------------------------------
__global__ __launch_bounds__(256)
void transpose_inplace_bf16(__bf16* __restrict__ W)
{
    const int bi = blockIdx.y;
    const int bj = blockIdx.x;
    if (bi > bj) return;
    __shared__ __bf16 ta[64][72];
    __shared__ __bf16 tb[64][72];
    const int tid = threadIdx.x;
    const int lr = tid >> 3;
    const int lc = (tid & 7) * 8;
    const size_t N = MEMN;
    __bf16* At = W + (size_t)bi * 64 * N + (size_t)bj * 64;
    __bf16* Bt = W + (size_t)bj * 64 * N + (size_t)bi * 64;
#pragma unroll
    for (int p = 0; p < 2; ++p) {
        const int rr = p * 32 + lr;
        *(bx8*)(&ta[rr][lc]) = *(const bx8*)(At + (size_t)rr * N + lc);
        *(bx8*)(&tb[rr][lc]) = *(const bx8*)(Bt + (size_t)rr * N + lc);
    }
    __syncthreads();
    const int oc = tid >> 2;
    const int ob = (tid & 3) * 16;
    bx8 u0, u1, v0, v1;
#pragma unroll
    for (int j = 0; j < 8; ++j) {
        u0[j] = tb[ob + j][oc];  u1[j] = tb[ob + 8 + j][oc];
        v0[j] = ta[ob + j][oc];  v1[j] = ta[ob + 8 + j][oc];
    }
    *(bx8*)(At + (size_t)oc * N + ob)     = u0;
    *(bx8*)(At + (size_t)oc * N + ob + 8) = u1;
    *(bx8*)(Bt + (size_t)oc * N + ob)     = v0;
    *(bx8*)(Bt + (size_t)oc * N + ob + 8) = v1;
}

// ---------------------------------------------------------------------------
// Row softmax over 8192 bf16 logits, in place. One block/row, fp32 math.
// ---------------------------------------------------------------------------
__global__ __launch_bounds__(256)
void softmax_rows(__bf16* __restrict__ W)
{
    __bf16* row = W + (size_t)blockIdx.x * MEMN;
    const int tid = threadIdx.x;
    float v[32];
#pragma unroll
    for (int i = 0; i < 4; ++i) {
        bx8 u = *(const bx8*)(row + i * 2048 + tid * 8);
#pragma unroll
        for (int j = 0; j < 8; ++j) v[i * 8 + j] = (float)u[j];
    }
    float m = -1e30f;
#pragma unroll
    for (int i = 0; i < 32; ++i) m = fmaxf(m, v[i]);
#pragma unroll
    for (int off = 32; off >= 1; off >>= 1) m = fmaxf(m, __shfl_xor(m, off, 64));
    __shared__ float red[8];
    const int wave = tid >> 6, lane = tid & 63;
    if (lane == 0) red[wave] = m;
    __syncthreads();
    m = fmaxf(fmaxf(red[0], red[1]), fmaxf(red[2], red[3]));
    float s = 0.f;
#pragma unroll
    for (int i = 0; i < 32; ++i) { v[i] = __expf(v[i] - m); s += v[i]; }
#pragma unroll
    for (int off = 32; off >= 1; off >>= 1) s += __shfl_xor(s, off, 64);
    if (lane == 0) red[4 + wave] = s;
    __syncthreads();
    s = (red[4] + red[5]) + (red[6] + red[7]);
    const float inv = 1.0f / s;
#pragma unroll
    for (int i = 0; i < 4; ++i) {
        bx8 u;
#pragma unroll
        for (int j = 0; j < 8; ++j) u[j] = (__bf16)(v[i * 8 + j] * inv);
        *(bx8*)(row + i * 2048 + tid * 8) = u;
    }
}

// ---------------------------------------------------------------------------
// NT GEMM, 8-phase-style pipelined: C[i,j] = sum_k A[i,k]*B[j,k].
// 128x256 tile, BK=32, 256 threads = 4 waves (2Mx2N), wave tile 64x128
// (FM=4, FN=8 -> MFMA:ds_read = 32:12, vs 2.0 before). Ring-3 LDS (72 KiB,
// 2 blocks/CU) of (A,B) K-slices; stage(t+2) issued split across the two
// phases of tile t; counted s_waitcnt vmcnt(6) at tile top (= stage(t+1) in
// flight) guarantees stage(t) landed (in-order vmcnt); vmcnt(0) only at the
// last tile. Each K-tile = 2 phases: {3 gloads || ds_read subtile -> barrier
// -> setprio(1) 16 MFMA setprio(0) -> barrier}  (m201 phase pattern).
// Both-sides XOR swizzle as round 3 (PMC-verified 0 bank conflicts).
// MODE 0: bf16 out + bias[j]; MODE 1: f32 out; MODE 2: f32 out + add[idx].
// ---------------------------------------------------------------------------
template <int MODE>
__global__ __launch_bounds__(256, 2)
void gemm4(const __bf16* __restrict__ A, const __bf16* __restrict__ B,
           const float* __restrict__ bias, const float* __restrict__ add,
           void* __restrict__ out, int N, int K, int nBN)
{
    constexpr int BM = 128, BN = 256;
    constexpr int ASZ = BM * 64;       // 8 KiB per A slot
    constexpr int BSZ = BN * 64;       // 16 KiB per B slot
    __shared__ __align__(16) char smem[3 * (ASZ + BSZ)];   // 72 KiB

    const int tid = threadIdx.x;
    const int wid = tid >> 6;
    const int ln  = tid & 63;
    const int fl  = ln & 15;
    const int fh  = ln >> 4;
    const int wr  = wid >> 1;          // 0..1
    const int wc  = wid & 1;           // 0..1

    // T1: bijective XCD swizzle (grids are multiples of 8)
    const int nwg = gridDim.x;
    const int bid = blockIdx.x;
    const int wg  = (bid & 7) * (nwg >> 3) + (bid >> 3);
    const int tm  = (wg / nBN) * BM;
    const int tn  = (wg % nBN) * BN;
    const int NT  = K / 32;

    // pre-swizzled global sources (rule 21: source permuted, LDS dest linear)
    const __bf16* Ag[2];
    const __bf16* Bg[4];
#pragma unroll
    for (int R = 0; R < 2; ++R) {
        const int p = R * 256 + tid;
        Ag[R] = A + (size_t)(tm + (p >> 2)) * K + (((p & 3) ^ ((p >> 2) & 3)) * 8);
    }
#pragma unroll
    for (int R = 0; R < 4; ++R) {
        const int p = R * 256 + tid;
        Bg[R] = B + (size_t)(tn + (p >> 2)) * K + (((p & 3) ^ ((p >> 2) & 3)) * 8);
    }
    char* const As = smem;
    char* const Bs = smem + 3 * ASZ;

    auto stageA = [&](int t) {     // 3 loads: A rounds 0,1 + B round 0
        const int s = t % 3;
        const size_t ko = (size_t)t * 32;
        GLDS(Ag[0] + ko, As + s * ASZ + wid * 1024);
        GLDS(Ag[1] + ko, As + s * ASZ + 4096 + wid * 1024);
        GLDS(Bg[0] + ko, Bs + s * BSZ + wid * 1024);
    };
    auto stageB = [&](int t) {     // 3 loads: B rounds 1..3
        const int s = t % 3;
        const size_t ko = (size_t)t * 32;
        GLDS(Bg[1] + ko, Bs + s * BSZ + 4096 + wid * 1024);
        GLDS(Bg[2] + ko, Bs + s * BSZ + 8192 + wid * 1024);
        GLDS(Bg[3] + ko, Bs + s * BSZ + 12288 + wid * 1024);
    };

    fx4 acc[4][8] = {};

    stageA(0); stageB(0);
    if (NT > 1) { stageA(1); stageB(1); }

    for (int t = 0; t < NT; ++t) {
        if (t >= NT - 1) asm volatile("s_waitcnt vmcnt(0)" ::: "memory");
        else             asm volatile("s_waitcnt vmcnt(6)" ::: "memory");
        __builtin_amdgcn_s_barrier();
        asm volatile("" ::: "memory");

        const char* Ab = As + (t % 3) * ASZ;
        const char* Bb = Bs + (t % 3) * BSZ;
        const bool pf = (t + 2 < NT);

        bx8 fa[4], fb[4];
        // ---------------- phase 0: ni 0..3 ----------------
        if (pf) stageA(t + 2);
#pragma unroll
        for (int mi = 0; mi < 4; ++mi) {
            const int r = wr * 64 + mi * 16 + fl;
            fa[mi] = *(const bx8*)(Ab + r * 64 + ((fh ^ (r & 3)) << 4));
        }
#pragma unroll
        for (int ni = 0; ni < 4; ++ni) {
            const int c = wc * 128 + ni * 16 + fl;
            fb[ni] = *(const bx8*)(Bb + c * 64 + ((fh ^ (c & 3)) << 4));
        }
        __builtin_amdgcn_s_barrier();
        asm volatile("" ::: "memory");
        __builtin_amdgcn_s_setprio(1);
#pragma unroll
        for (int mi = 0; mi < 4; ++mi)
#pragma unroll
            for (int ni = 0; ni < 4; ++ni)
                acc[mi][ni] = __builtin_amdgcn_mfma_f32_16x16x32_bf16(
                    fa[mi], fb[ni], acc[mi][ni], 0, 0, 0);
        __builtin_amdgcn_s_setprio(0);
        __builtin_amdgcn_s_barrier();
        asm volatile("" ::: "memory");

        // ---------------- phase 1: ni 4..7 ----------------
        if (pf) stageB(t + 2);
#pragma unroll
        for (int ni = 0; ni < 4; ++ni) {
            const int c = wc * 128 + (ni + 4) * 16 + fl;
            fb[ni] = *(const bx8*)(Bb + c * 64 + ((fh ^ (c & 3)) << 4));
        }
        __builtin_amdgcn_s_barrier();
        asm volatile("" ::: "memory");
        __builtin_amdgcn_s_setprio(1);
#pragma unroll
        for (int mi = 0; mi < 4; ++mi)
#pragma unroll
            for (int ni = 0; ni < 4; ++ni)
                acc[mi][ni + 4] = __builtin_amdgcn_mfma_f32_16x16x32_bf16(
                    fa[mi], fb[ni], acc[mi][ni + 4], 0, 0, 0);
        __builtin_amdgcn_s_setprio(0);
        // loop-top barrier closes the phase
    }

    // epilogue: C/D layout col = lane&15, row = (lane>>4)*4 + reg
#pragma unroll
    for (int mi = 0; mi < 4; ++mi) {
#pragma unroll
        for (int ni = 0; ni < 8; ++ni) {
            const int gr0 = tm + wr * 64 + mi * 16 + fh * 4;
            const int gc  = tn + wc * 128 + ni * 16 + fl;
            fx4 c = acc[mi][ni];
            if constexpr (MODE == 0) {
                __bf16* O = (__bf16*)out;
                const float bv = bias[gc];
#pragma unroll
                for (int j = 0; j < 4; ++j)
                    O[(size_t)(gr0 + j) * N + gc] = (__bf16)(c[j] + bv);
            } else if constexpr (MODE == 1) {
                float* O = (float*)out;
#pragma unroll
                for (int j = 0; j < 4; ++j)
                    O[(size_t)(gr0 + j) * N + gc] = c[j];
            } else {
                float* O = (float*)out;
#pragma unroll
                for (int j = 0; j < 4; ++j) {
                    const size_t idx = (size_t)(gr0 + j) * N + gc;
                    O[idx] = c[j] + add[idx];
                }
            }
        }
    }
}

// ---------------------------------------------------------------------------
// Orchestration. ws layout (176 MiB):
//   xb    [8192,1024] bf16  @ 0
//   slot1 [8192,1024] bf16  @ 16 MiB  (rwb then wwb)
//   slot2 [1024,8192] bf16  @ 32 MiB  (memT then xT)
//   W     [8192,8192] bf16  @ 48 MiB
// ---------------------------------------------------------------------------
extern "C" void kernel_launch(void* const* d_in, const int* in_sizes, int n_in,
                              void* d_out, int out_size, void* d_ws, size_t ws_size,
                              hipStream_t stream)
{
    const float* x       = (const float*)d_in[0];
    const float* memory  = (const float*)d_in[1];
    const float* read_w  = (const float*)d_in[2];
    const float* read_b  = (const float*)d_in[3];
    const float* write_w = (const float*)d_in[4];
    const float* write_b = (const float*)d_in[5];

    float* out_read = (float*)d_out;
    float* out_mem  = (float*)d_out + (size_t)MEMN * HID;

    char* p = (char*)d_ws;
    const size_t MiB = 1024 * 1024;
    __bf16* xb    = (__bf16*)(p + 0 * MiB);
    __bf16* slot1 = (__bf16*)(p + 16 * MiB);
    __bf16* slot2 = (__bf16*)(p + 32 * MiB);
    __bf16* W     = (__bf16*)(p + 48 * MiB);

    // ---- read path ---------------------------------------------------------
    f32_to_bf16_vec<<<4096, 256, 0, stream>>>(x, xb);
    f32_to_bf16_vec<<<4096, 256, 0, stream>>>(read_w, slot1);
    transpose_f32_to_bf16<<<dim3(HID / 64, ROWS / 64), 256, 0, stream>>>(memory, slot2, ROWS, HID);
    gemm4<0><<<(ROWS / 128) * (MEMN / 256), 256, 0, stream>>>(
        xb, slot1, read_b, nullptr, W, MEMN, HID, MEMN / 256);
    softmax_rows<<<ROWS, 256, 0, stream>>>(W);
    gemm4<1><<<(ROWS / 128) * (HID / 256), 256, 0, stream>>>(
        W, slot2, nullptr, nullptr, out_read, HID, MEMN, HID / 256);

    // ---- write path --------------------------------------------------------
    f32_to_bf16_vec<<<4096, 256, 0, stream>>>(write_w, slot1);
    transpose_f32_to_bf16<<<dim3(HID / 64, ROWS / 64), 256, 0, stream>>>(x, slot2, ROWS, HID);
    gemm4<0><<<(ROWS / 128) * (MEMN / 256), 256, 0, stream>>>(
        xb, slot1, write_b, nullptr, W, MEMN, HID, MEMN / 256);
    softmax_rows<<<ROWS, 256, 0, stream>>>(W);
    transpose_inplace_bf16<<<dim3(MEMN / 64, MEMN / 64), 256, 0, stream>>>(W);
    gemm4<2><<<(MEMN / 128) * (HID / 256), 256, 0, stream>>>(
        W, slot2, nullptr, memory, out_mem, HID, ROWS, HID / 256);
}

// Round 5
// 757.647 us; speedup vs baseline: 1.1833x; 1.1833x over previous
//
#include <hip/hip_runtime.h>
#include <hip/hip_bf16.h>

typedef __attribute__((ext_vector_type(8))) __bf16 bx8;
typedef __attribute__((ext_vector_type(4))) float  fx4;

#define ROWS 8192   // B*S
#define HID  1024
#define MEMN 8192

// global_load_lds, 16B per lane; LDS dest = wave-uniform base + lane*16
#define GLDS(gp, lp) __builtin_amdgcn_global_load_lds( \
    (const __attribute__((address_space(1))) void*)(gp), \
    (__attribute__((address_space(3))) void*)(lp), 16, 0, 0)

// ---------------------------------------------------------------------------
// fp32 -> bf16 elementwise convert
// ---------------------------------------------------------------------------
__global__ __launch_bounds__(256)
void f32_to_bf16_vec(const float* __restrict__ in, __bf16* __restrict__ out)
{
    const size_t i = ((size_t)blockIdx.x * 256 + threadIdx.x) * 8;
    fx4 a = *(const fx4*)(in + i);
    fx4 b = *(const fx4*)(in + i + 4);
    bx8 u;
    u[0] = (__bf16)a[0]; u[1] = (__bf16)a[1]; u[2] = (__bf16)a[2]; u[3] = (__bf16)a[3];
    u[4] = (__bf16)b[0]; u[5] = (__bf16)b[1]; u[6] = (__bf16)b[2]; u[7] = (__bf16)b[3];
    *(bx8*)(out + i) = u;
}

// ---------------------------------------------------------------------------
// fp32 [R][C] -> bf16 [C][R] transpose (64x64 tiles via LDS)
// ---------------------------------------------------------------------------
__global__ __launch_bounds__(256)
void transpose_f32_to_bf16(const float* __restrict__ in, __bf16* __restrict__ out,
                           int R, int C)
{
    __shared__ float t[64][65];
    const int tid = threadIdx.x;
    const int r0 = blockIdx.y * 64;
    const int c0 = blockIdx.x * 64;
    const int lr = tid >> 4;
    const int lc = (tid & 15) * 4;
#pragma unroll
    for (int p = 0; p < 4; ++p) {
        const int rr = p * 16 + lr;
        const fx4 v = *(const fx4*)(in + (size_t)(r0 + rr) * C + c0 + lc);
        t[rr][lc + 0] = v[0]; t[rr][lc + 1] = v[1];
        t[rr][lc + 2] = v[2]; t[rr][lc + 3] = v[3];
    }
    __syncthreads();
    const int oc = tid >> 2;
    const int ob = (tid & 3) * 16;
    bx8 u0, u1;
#pragma unroll
    for (int j = 0; j < 8; ++j) {
        u0[j] = (__bf16)t[ob + j][oc];
        u1[j] = (__bf16)t[ob + 8 + j][oc];
    }
    *(bx8*)(out + (size_t)(c0 + oc) * R + r0 + ob)     = u0;
    *(bx8*)(out + (size_t)(c0 + oc) * R + r0 + ob + 8) = u1;
}

// ---------------------------------------------------------------------------
// In-place transpose of square bf16 matrix W [MEMN][MEMN], 64x64 tile pairs.
// ---------------------------------------------------------------------------
__global__ __launch_bounds__(256)
void transpose_inplace_bf16(__bf16* __restrict__ W)
{
    const int bi = blockIdx.y;
    const int bj = blockIdx.x;
    if (bi > bj) return;
    __shared__ __bf16 ta[64][72];
    __shared__ __bf16 tb[64][72];
    const int tid = threadIdx.x;
    const int lr = tid >> 3;
    const int lc = (tid & 7) * 8;
    const size_t N = MEMN;
    __bf16* At = W + (size_t)bi * 64 * N + (size_t)bj * 64;
    __bf16* Bt = W + (size_t)bj * 64 * N + (size_t)bi * 64;
#pragma unroll
    for (int p = 0; p < 2; ++p) {
        const int rr = p * 32 + lr;
        *(bx8*)(&ta[rr][lc]) = *(const bx8*)(At + (size_t)rr * N + lc);
        *(bx8*)(&tb[rr][lc]) = *(const bx8*)(Bt + (size_t)rr * N + lc);
    }
    __syncthreads();
    const int oc = tid >> 2;
    const int ob = (tid & 3) * 16;
    bx8 u0, u1, v0, v1;
#pragma unroll
    for (int j = 0; j < 8; ++j) {
        u0[j] = tb[ob + j][oc];  u1[j] = tb[ob + 8 + j][oc];
        v0[j] = ta[ob + j][oc];  v1[j] = ta[ob + 8 + j][oc];
    }
    *(bx8*)(At + (size_t)oc * N + ob)     = u0;
    *(bx8*)(At + (size_t)oc * N + ob + 8) = u1;
    *(bx8*)(Bt + (size_t)oc * N + ob)     = v0;
    *(bx8*)(Bt + (size_t)oc * N + ob + 8) = v1;
}

// ---------------------------------------------------------------------------
// Row softmax over 8192 bf16 logits, in place. One block/row, fp32 math.
// ---------------------------------------------------------------------------
__global__ __launch_bounds__(256)
void softmax_rows(__bf16* __restrict__ W)
{
    __bf16* row = W + (size_t)blockIdx.x * MEMN;
    const int tid = threadIdx.x;
    float v[32];
#pragma unroll
    for (int i = 0; i < 4; ++i) {
        bx8 u = *(const bx8*)(row + i * 2048 + tid * 8);
#pragma unroll
        for (int j = 0; j < 8; ++j) v[i * 8 + j] = (float)u[j];
    }
    float m = -1e30f;
#pragma unroll
    for (int i = 0; i < 32; ++i) m = fmaxf(m, v[i]);
#pragma unroll
    for (int off = 32; off >= 1; off >>= 1) m = fmaxf(m, __shfl_xor(m, off, 64));
    __shared__ float red[8];
    const int wave = tid >> 6, lane = tid & 63;
    if (lane == 0) red[wave] = m;
    __syncthreads();
    m = fmaxf(fmaxf(red[0], red[1]), fmaxf(red[2], red[3]));
    float s = 0.f;
#pragma unroll
    for (int i = 0; i < 32; ++i) { v[i] = __expf(v[i] - m); s += v[i]; }
#pragma unroll
    for (int off = 32; off >= 1; off >>= 1) s += __shfl_xor(s, off, 64);
    if (lane == 0) red[4 + wave] = s;
    __syncthreads();
    s = (red[4] + red[5]) + (red[6] + red[7]);
    const float inv = 1.0f / s;
#pragma unroll
    for (int i = 0; i < 4; ++i) {
        bx8 u;
#pragma unroll
        for (int j = 0; j < 8; ++j) u[j] = (__bf16)(v[i * 8 + j] * inv);
        *(bx8*)(row + i * 2048 + tid * 8) = u;
    }
}

// ---------------------------------------------------------------------------
// gemm8: round-3 verified NT GEMM (unchanged; used for the two PV GEMMs).
// ---------------------------------------------------------------------------
template <int BM, int BN, int MODE>
__global__ __launch_bounds__(512)
void gemm8(const __bf16* __restrict__ A, const __bf16* __restrict__ B,
           const float* __restrict__ bias, const float* __restrict__ add,
           void* __restrict__ out, int N, int K, int nBN)
{
    constexpr int ASZ = BM * 64;
    constexpr int BSZ = BN * 64;
    constexpr int RA  = BM / 128;
    constexpr int RB  = BN / 128;
    constexpr int L   = RA + RB;
    constexpr int RWM = BM / 2, RWN = BN / 4;
    constexpr int FM  = RWM / 16, FN = RWN / 16;

    __shared__ __align__(16) char smem[4 * (ASZ + BSZ)];

    const int tid = threadIdx.x;
    const int wid = tid >> 6;
    const int ln  = tid & 63;
    const int fl  = ln & 15;
    const int fh  = ln >> 4;
    const int wr  = wid >> 2;
    const int wc  = wid & 3;

    const int nwg = gridDim.x;
    const int bid = blockIdx.x;
    const int wg  = (bid & 7) * (nwg >> 3) + (bid >> 3);
    const int tm  = (wg / nBN) * BM;
    const int tn  = (wg % nBN) * BN;

    const int NT = K / 32;

    const __bf16* Ag[RA];
    const __bf16* Bg[RB];
#pragma unroll
    for (int R = 0; R < RA; ++R) {
        const int p = R * 512 + tid;
        Ag[R] = A + (size_t)(tm + (p >> 2)) * K + ((p & 3) ^ ((p >> 3) & 3)) * 8;
    }
#pragma unroll
    for (int R = 0; R < RB; ++R) {
        const int p = R * 512 + tid;
        Bg[R] = B + (size_t)(tn + (p >> 2)) * K + ((p & 3) ^ ((p >> 3) & 3)) * 8;
    }

    auto stage = [&](int t) {
        const int s = t & 3;
        const size_t ko = (size_t)t * 32;
        char* Ad = smem + s * ASZ + wid * 1024;
        char* Bd = smem + 4 * ASZ + s * BSZ + wid * 1024;
#pragma unroll
        for (int R = 0; R < RA; ++R) GLDS(Ag[R] + ko, Ad + R * 8192);
#pragma unroll
        for (int R = 0; R < RB; ++R) GLDS(Bg[R] + ko, Bd + R * 8192);
    };

    fx4 acc[FM][FN] = {};

    stage(0);
    if (NT > 1) stage(1);

    for (int t = 0; t < NT; ++t) {
        if (t == NT - 1) {
            asm volatile("s_waitcnt vmcnt(0)" ::: "memory");
        } else if constexpr (L == 4) {
            asm volatile("s_waitcnt vmcnt(4)" ::: "memory");
        } else {
            asm volatile("s_waitcnt vmcnt(3)" ::: "memory");
        }
        __builtin_amdgcn_s_barrier();
        asm volatile("" ::: "memory");
        if (t + 2 < NT) stage(t + 2);

        const char* Ab = smem + (t & 3) * ASZ;
        const char* Bb = smem + 4 * ASZ + (t & 3) * BSZ;
        bx8 fa[FM], fb[FN];
#pragma unroll
        for (int mi = 0; mi < FM; ++mi) {
            const int r = wr * RWM + mi * 16 + fl;
            fa[mi] = *(const bx8*)(Ab + r * 64 + ((fh ^ ((r >> 1) & 3)) << 4));
        }
#pragma unroll
        for (int ni = 0; ni < FN; ++ni) {
            const int c = wc * RWN + ni * 16 + fl;
            fb[ni] = *(const bx8*)(Bb + c * 64 + ((fh ^ ((c >> 1) & 3)) << 4));
        }
        __builtin_amdgcn_s_setprio(1);
#pragma unroll
        for (int mi = 0; mi < FM; ++mi)
#pragma unroll
            for (int ni = 0; ni < FN; ++ni)
                acc[mi][ni] = __builtin_amdgcn_mfma_f32_16x16x32_bf16(
                    fa[mi], fb[ni], acc[mi][ni], 0, 0, 0);
        __builtin_amdgcn_s_setprio(0);
    }

#pragma unroll
    for (int mi = 0; mi < FM; ++mi) {
#pragma unroll
        for (int ni = 0; ni < FN; ++ni) {
            const int gr0 = tm + wr * RWM + mi * 16 + fh * 4;
            const int gc  = tn + wc * RWN + ni * 16 + fl;
            fx4 c = acc[mi][ni];
            if constexpr (MODE == 0) {
                __bf16* O = (__bf16*)out;
                const float bv = bias[gc];
#pragma unroll
                for (int j = 0; j < 4; ++j)
                    O[(size_t)(gr0 + j) * N + gc] = (__bf16)(c[j] + bv);
            } else if constexpr (MODE == 1) {
                float* O = (float*)out;
#pragma unroll
                for (int j = 0; j < 4; ++j)
                    O[(size_t)(gr0 + j) * N + gc] = c[j];
            } else {
                float* O = (float*)out;
#pragma unroll
                for (int j = 0; j < 4; ++j) {
                    const size_t idx = (size_t)(gr0 + j) * N + gc;
                    O[idx] = c[j] + add[idx];
                }
            }
        }
    }
}

// ---------------------------------------------------------------------------
// gemm_dp: deep-pipelined 256x256 NT GEMM (m201-class schedule), logits only.
// BK=64, 512 thr = 8 waves (2Mx4N), wave tile 128x64, acc[8][4].
// LDS: 2-slot dbuf x (A 256x64 + B 256x64) bf16 = 128 KiB.
//   A slot layout: row-major [256 rows][64 k] (128 B/row); 16B granule at
//   (row, g) holds source k-granule g ^ (row&7)  [both-sides involution].
//   Staging round r (8 KiB = 512 lanes x 16B) covers rows 64r..64r+63, LDS
//   linear; source col pre-swizzled per lane. Read granule (kk*4+fh)^(row&7)
//   -> 8 positions x 8 lanes = minimal bank aliasing (conflict-free).
// Per K-tile t: 4 phases (mh,kk) = (0,0),(1,0),(0,1),(1,1). Each phase:
//   issue 2 staging gloads of tile t+1 (order B0,B1 | B2,B3 | A0,A1 | A2,A3)
//   -> ds_read fa[4] (+fb[4] at kk start) -> setprio(1) 16 MFMA setprio(0)
//   -> counted wait + barrier.
// Waits (issue positions B0..B3=0..3, A0..A3=4..7 per tile):
//   end ph0: vmcnt(2)  [A3(t) landed; 2 of t+1 outstanding]  (vmcnt(0) last tile)
//   end ph3: vmcnt(1)  [all of t+1 except A3 landed]
//   Never drains mid-loop. Race-free: stage(t+1) writes slot (t+1)&1; reads
//   of that slot's old data ended >=4 barriers earlier (waves within one
//   barrier interval).
// ---------------------------------------------------------------------------
__global__ __launch_bounds__(512, 2)
void gemm_dp(const __bf16* __restrict__ A, const __bf16* __restrict__ B,
             const float* __restrict__ bias, __bf16* __restrict__ out,
             int N, int K, int nBN)
{
    constexpr int SLOT = 256 * 64 * 2;             // 32 KiB
    __shared__ __align__(16) char smem[4 * SLOT];  // A: slots 0-1, B: slots 2-3
    char* const As = smem;
    char* const Bs = smem + 2 * SLOT;

    const int tid = threadIdx.x;
    const int wid = tid >> 6;
    const int ln  = tid & 63;
    const int fl  = ln & 15;
    const int fh  = ln >> 4;
    const int wr  = wid >> 2;          // 0..1 -> rows wr*128
    const int wc  = wid & 3;           // 0..3 -> cols wc*64

    const int nwg = gridDim.x;
    const int bid = blockIdx.x;
    const int wg  = (bid & 7) * (nwg >> 3) + (bid >> 3);
    const int tm  = (wg / nBN) * 256;
    const int tn  = (wg % nBN) * 256;
    const int NT  = K / 64;

    // staging source: thread covers row (64r + tid>>3), src k-granule
    // (tid&7)^((tid>>3)&7); +t*64 k-offset per tile.
    const int trow = tid >> 3;
    const int tg   = ((tid & 7) ^ ((tid >> 3) & 7)) * 8;
    const __bf16* Asrc = A + (size_t)(tm + trow) * K + tg;
    const __bf16* Bsrc = B + (size_t)(tn + trow) * K + tg;
    const int ldst = wid * 1024;       // + lane*16 implicit in GLDS

    auto stA = [&](int t, int r) {
        GLDS(Asrc + (size_t)(r << 6) * K + t * 64,
             As + (t & 1) * SLOT + r * 8192 + ldst);
    };
    auto stB = [&](int t, int r) {
        GLDS(Bsrc + (size_t)(r << 6) * K + t * 64,
             Bs + (t & 1) * SLOT + r * 8192 + ldst);
    };

    fx4 acc[8][4] = {};

    // prologue: stage tile 0 fully (positions B0..B3, A0..A3)
#pragma unroll
    for (int r = 0; r < 4; ++r) stB(0, r);
#pragma unroll
    for (int r = 0; r < 4; ++r) stA(0, r);
    asm volatile("s_waitcnt vmcnt(1)" ::: "memory");
    __builtin_amdgcn_s_barrier();
    asm volatile("" ::: "memory");

    for (int t = 0; t < NT; ++t) {
        const char* Ab = As + (t & 1) * SLOT;
        const char* Bb = Bs + (t & 1) * SLOT;
        const bool pf = (t + 1 < NT);
        bx8 fa[4], fb[4];

        // ---- phase 0: (mh=0, kk=0) ----
        if (pf) { stB(t + 1, 0); stB(t + 1, 1); }
#pragma unroll
        for (int ni = 0; ni < 4; ++ni) {
            const int c = wc * 64 + ni * 16 + fl;
            fb[ni] = *(const bx8*)(Bb + c * 128 + (((0 + fh) ^ (c & 7)) << 4));
        }
#pragma unroll
        for (int mi = 0; mi < 4; ++mi) {
            const int r = wr * 128 + mi * 16 + fl;
            fa[mi] = *(const bx8*)(Ab + r * 128 + (((0 + fh) ^ (r & 7)) << 4));
        }
        __builtin_amdgcn_s_setprio(1);
#pragma unroll
        for (int mi = 0; mi < 4; ++mi)
#pragma unroll
            for (int ni = 0; ni < 4; ++ni)
                acc[mi][ni] = __builtin_amdgcn_mfma_f32_16x16x32_bf16(
                    fa[mi], fb[ni], acc[mi][ni], 0, 0, 0);
        __builtin_amdgcn_s_setprio(0);
        if (pf) asm volatile("s_waitcnt vmcnt(2)" ::: "memory");
        else    asm volatile("s_waitcnt vmcnt(0)" ::: "memory");
        __builtin_amdgcn_s_barrier();
        asm volatile("" ::: "memory");

        // ---- phase 1: (mh=1, kk=0) ----
        if (pf) { stB(t + 1, 2); stB(t + 1, 3); }
#pragma unroll
        for (int mi = 0; mi < 4; ++mi) {
            const int r = wr * 128 + 64 + mi * 16 + fl;
            fa[mi] = *(const bx8*)(Ab + r * 128 + (((0 + fh) ^ (r & 7)) << 4));
        }
        __builtin_amdgcn_s_setprio(1);
#pragma unroll
        for (int mi = 0; mi < 4; ++mi)
#pragma unroll
            for (int ni = 0; ni < 4; ++ni)
                acc[4 + mi][ni] = __builtin_amdgcn_mfma_f32_16x16x32_bf16(
                    fa[mi], fb[ni], acc[4 + mi][ni], 0, 0, 0);
        __builtin_amdgcn_s_setprio(0);
        __builtin_amdgcn_s_barrier();
        asm volatile("" ::: "memory");

        // ---- phase 2: (mh=0, kk=1) ----
        if (pf) { stA(t + 1, 0); stA(t + 1, 1); }
#pragma unroll
        for (int ni = 0; ni < 4; ++ni) {
            const int c = wc * 64 + ni * 16 + fl;
            fb[ni] = *(const bx8*)(Bb + c * 128 + (((4 + fh) ^ (c & 7)) << 4));
        }
#pragma unroll
        for (int mi = 0; mi < 4; ++mi) {
            const int r = wr * 128 + mi * 16 + fl;
            fa[mi] = *(const bx8*)(Ab + r * 128 + (((4 + fh) ^ (r & 7)) << 4));
        }
        __builtin_amdgcn_s_setprio(1);
#pragma unroll
        for (int mi = 0; mi < 4; ++mi)
#pragma unroll
            for (int ni = 0; ni < 4; ++ni)
                acc[mi][ni] = __builtin_amdgcn_mfma_f32_16x16x32_bf16(
                    fa[mi], fb[ni], acc[mi][ni], 0, 0, 0);
        __builtin_amdgcn_s_setprio(0);
        __builtin_amdgcn_s_barrier();
        asm volatile("" ::: "memory");

        // ---- phase 3: (mh=1, kk=1) ----
        if (pf) { stA(t + 1, 2); stA(t + 1, 3); }
#pragma unroll
        for (int mi = 0; mi < 4; ++mi) {
            const int r = wr * 128 + 64 + mi * 16 + fl;
            fa[mi] = *(const bx8*)(Ab + r * 128 + (((4 + fh) ^ (r & 7)) << 4));
        }
        __builtin_amdgcn_s_setprio(1);
#pragma unroll
        for (int mi = 0; mi < 4; ++mi)
#pragma unroll
            for (int ni = 0; ni < 4; ++ni)
                acc[4 + mi][ni] = __builtin_amdgcn_mfma_f32_16x16x32_bf16(
                    fa[mi], fb[ni], acc[4 + mi][ni], 0, 0, 0);
        __builtin_amdgcn_s_setprio(0);
        asm volatile("s_waitcnt vmcnt(1)" ::: "memory");
        __builtin_amdgcn_s_barrier();
        asm volatile("" ::: "memory");
    }

    // epilogue: bf16 out + bias (MODE 0 semantics)
#pragma unroll
    for (int mh = 0; mh < 2; ++mh)
#pragma unroll
        for (int mi = 0; mi < 4; ++mi)
#pragma unroll
            for (int ni = 0; ni < 4; ++ni) {
                const int gr0 = tm + wr * 128 + mh * 64 + mi * 16 + fh * 4;
                const int gc  = tn + wc * 64 + ni * 16 + fl;
                const float bv = bias[gc];
                fx4 c = acc[mh * 4 + mi][ni];
#pragma unroll
                for (int j = 0; j < 4; ++j)
                    out[(size_t)(gr0 + j) * N + gc] = (__bf16)(c[j] + bv);
            }
}

// ---------------------------------------------------------------------------
// Orchestration. ws layout (176 MiB):
//   xb    [8192,1024] bf16  @ 0
//   slot1 [8192,1024] bf16  @ 16 MiB  (rwb then wwb)
//   slot2 [1024,8192] bf16  @ 32 MiB  (memT then xT)
//   W     [8192,8192] bf16  @ 48 MiB
// ---------------------------------------------------------------------------
extern "C" void kernel_launch(void* const* d_in, const int* in_sizes, int n_in,
                              void* d_out, int out_size, void* d_ws, size_t ws_size,
                              hipStream_t stream)
{
    const float* x       = (const float*)d_in[0];
    const float* memory  = (const float*)d_in[1];
    const float* read_w  = (const float*)d_in[2];
    const float* read_b  = (const float*)d_in[3];
    const float* write_w = (const float*)d_in[4];
    const float* write_b = (const float*)d_in[5];

    float* out_read = (float*)d_out;
    float* out_mem  = (float*)d_out + (size_t)MEMN * HID;

    char* p = (char*)d_ws;
    const size_t MiB = 1024 * 1024;
    __bf16* xb    = (__bf16*)(p + 0 * MiB);
    __bf16* slot1 = (__bf16*)(p + 16 * MiB);
    __bf16* slot2 = (__bf16*)(p + 32 * MiB);
    __bf16* W     = (__bf16*)(p + 48 * MiB);

    // ---- read path ---------------------------------------------------------
    f32_to_bf16_vec<<<4096, 256, 0, stream>>>(x, xb);
    f32_to_bf16_vec<<<4096, 256, 0, stream>>>(read_w, slot1);
    transpose_f32_to_bf16<<<dim3(HID / 64, ROWS / 64), 256, 0, stream>>>(memory, slot2, ROWS, HID);
    gemm_dp<<<(ROWS / 256) * (MEMN / 256), 512, 0, stream>>>(
        xb, slot1, read_b, W, MEMN, HID, MEMN / 256);
    softmax_rows<<<ROWS, 256, 0, stream>>>(W);
    gemm8<128, 256, 1><<<(ROWS / 128) * (HID / 256), 512, 0, stream>>>(
        W, slot2, nullptr, nullptr, out_read, HID, MEMN, HID / 256);

    // ---- write path --------------------------------------------------------
    f32_to_bf16_vec<<<4096, 256, 0, stream>>>(write_w, slot1);
    transpose_f32_to_bf16<<<dim3(HID / 64, ROWS / 64), 256, 0, stream>>>(x, slot2, ROWS, HID);
    gemm_dp<<<(ROWS / 256) * (MEMN / 256), 512, 0, stream>>>(
        xb, slot1, write_b, W, MEMN, HID, MEMN / 256);
    softmax_rows<<<ROWS, 256, 0, stream>>>(W);
    transpose_inplace_bf16<<<dim3(MEMN / 64, MEMN / 64), 256, 0, stream>>>(W);
    gemm8<128, 256, 2><<<(MEMN / 128) * (HID / 256), 512, 0, stream>>>(
        W, slot2, nullptr, memory, out_mem, HID, ROWS, HID / 256);
}